// Round 1
// baseline (111.110 us; speedup 1.0000x reference)
//
#include <hip/hip_runtime.h>

// Freeverb, parallelized via closed-form expansion of the lagged recurrences.
//
// Comb (per filter):  y[t] = x[t-D] + fb*y[t-D]    (y=0 for t<D)
//   => y[t] = sum_{m>=1, t-mD>=0} fb^(m-1) * x[t-mD]     (<= ~29 terms)
// Allpass:  bo[t] = y[t-D] + fb*bo[t-D];  out[t] = bo[t] - y[t]
//   => bo[t] = sum_{m>=1, t-mD>=0} fb^(m-1) * y[t-mD]
//   truncated when |fb^(m-1)| <= 1e-10 (fb=0.5 -> ~33 terms; error << 0.16 thr)
//
// Schedule (5 dispatches, serial deps between allpass stages only):
//   comb_kernel -> ap(0) -> ap(1) -> ap(2) -> ap(3)+mix

__global__ __launch_bounds__(256) void comb_kernel(
    const float* __restrict__ x,
    const float* __restrict__ fbL, const float* __restrict__ fbR,
    const int* __restrict__ dL, const int* __restrict__ dR,
    float* __restrict__ yL, float* __restrict__ yR, int T)
{
    int gid = blockIdx.x * 256 + threadIdx.x;   // 16 threads per sample
    int t = gid >> 4;
    if (t >= T) return;
    int f = gid & 15;        // lane bits 0-3: filter id
    int c = f & 7;           // comb index
    int right = f >> 3;      // channel bit
    int D = right ? dR[c] : dL[c];
    float fb = right ? fbR[c] : fbL[c];

    float acc = 0.f, coef = 1.f;
    int idx = t - D;
    while (idx >= 0) {
        acc = fmaf(coef, x[idx], acc);
        coef *= fb;
        idx -= D;
    }
    // reduce the 8 combs of this channel (lane bits 0..2)
    acc += __shfl_xor(acc, 1);
    acc += __shfl_xor(acc, 2);
    acc += __shfl_xor(acc, 4);
    if (c == 0) {
        if (right) yR[t] = acc; else yL[t] = acc;
    }
}

__global__ __launch_bounds__(256) void ap_kernel(
    const float* __restrict__ inL, const float* __restrict__ inR,
    const float* __restrict__ fbLarr, const float* __restrict__ fbRarr,
    const int* __restrict__ dLarr, const int* __restrict__ dRarr,
    int stage, int is_final,
    float* __restrict__ outL, float* __restrict__ outR,
    const float* __restrict__ x,
    const float* __restrict__ wetp, const float* __restrict__ dryp,
    const float* __restrict__ widthp,
    float* __restrict__ out2, int T)
{
    int gid = blockIdx.x * 256 + threadIdx.x;   // 8 threads per sample
    int t = gid >> 3;
    if (t >= T) return;
    int j = gid & 3;                 // 4-way split of the m-series
    int right = (gid >> 2) & 1;      // channel bit (lane bit 2)
    int D = right ? dRarr[stage] : dLarr[stage];
    float fb = right ? fbRarr[stage] : fbLarr[stage];
    const float* __restrict__ in = right ? inR : inL;

    // coef = fb^j ; series ratio per thread is fb^4
    float coef = 1.f;
    #pragma unroll
    for (int k = 0; k < 3; ++k) if (k < j) coef *= fb;
    float fb4 = fb * fb; fb4 *= fb4;

    float acc = 0.f;
    int idx = t - (j + 1) * D;
    int step = 4 * D;
    while (idx >= 0 && fabsf(coef) > 1e-10f) {
        acc = fmaf(coef, in[idx], acc);
        coef *= fb4;
        idx -= step;
    }
    // reduce the 4 j-slices (lane bits 0..1)
    acc += __shfl_xor(acc, 1);
    acc += __shfl_xor(acc, 2);
    float y = acc - in[t];           // allpass output: -y_in + bo

    if (!is_final) {
        if (j == 0) { if (right) outR[t] = y; else outL[t] = y; }
    } else {
        float other = __shfl_xor(y, 4);   // exchange channels (lane bit 2)
        float wet = wetp[0], dry = dryp[0], width = widthp[0];
        float wet1 = wet * (width + 1.f) * 0.5f;
        float wet2 = wet * (1.f - width) * 0.5f;
        float o = fmaf(y, wet1, fmaf(other, wet2, x[t] * dry));
        if (j == 0) out2[2 * t + right] = o;   // interleaved [T,2]
    }
}

extern "C" void kernel_launch(void* const* d_in, const int* in_sizes, int n_in,
                              void* d_out, int out_size, void* d_ws, size_t ws_size,
                              hipStream_t stream) {
    const float* x           = (const float*)d_in[0];
    const float* comb_fb_L   = (const float*)d_in[1];
    const float* comb_fb_R   = (const float*)d_in[2];
    const float* ap_fb_L     = (const float*)d_in[3];
    const float* ap_fb_R     = (const float*)d_in[4];
    const float* wet         = (const float*)d_in[5];
    const float* dry         = (const float*)d_in[6];
    const float* width       = (const float*)d_in[7];
    const int*   comb_delay_L = (const int*)d_in[8];
    const int*   comb_delay_R = (const int*)d_in[9];
    const int*   ap_delay_L   = (const int*)d_in[10];
    const int*   ap_delay_R   = (const int*)d_in[11];
    const int T = in_sizes[0];

    float* w   = (float*)d_ws;          // 4*T floats used
    float* yL0 = w;
    float* yR0 = w + T;
    float* yL1 = w + 2 * (size_t)T;
    float* yR1 = w + 3 * (size_t)T;
    float* out = (float*)d_out;

    int cb = (16 * T + 255) / 256;
    int ab = (8 * T + 255) / 256;

    comb_kernel<<<cb, 256, 0, stream>>>(x, comb_fb_L, comb_fb_R,
                                        comb_delay_L, comb_delay_R, yL0, yR0, T);

    ap_kernel<<<ab, 256, 0, stream>>>(yL0, yR0, ap_fb_L, ap_fb_R,
                                      ap_delay_L, ap_delay_R, 0, 0,
                                      yL1, yR1, x, wet, dry, width, out, T);
    ap_kernel<<<ab, 256, 0, stream>>>(yL1, yR1, ap_fb_L, ap_fb_R,
                                      ap_delay_L, ap_delay_R, 1, 0,
                                      yL0, yR0, x, wet, dry, width, out, T);
    ap_kernel<<<ab, 256, 0, stream>>>(yL0, yR0, ap_fb_L, ap_fb_R,
                                      ap_delay_L, ap_delay_R, 2, 0,
                                      yL1, yR1, x, wet, dry, width, out, T);
    ap_kernel<<<ab, 256, 0, stream>>>(yL1, yR1, ap_fb_L, ap_fb_R,
                                      ap_delay_L, ap_delay_R, 3, 1,
                                      nullptr, nullptr, x, wet, dry, width, out, T);
}